// Round 22
// baseline (48.951 us; speedup 1.0000x reference)
//
#include <hip/hip_runtime.h>
#include <hip/hip_bf16.h>
#include <hip/hip_fp16.h>

typedef unsigned short u16;
typedef __attribute__((ext_vector_type(4))) short short4v;

#define NF 2
#define NLOC 4096
#define NALL 8192
#define NNEI_ 138
#define KNOTS 1024          // knots per type; u_k = k/KNOTS, s = A*u/(1-u)
#define ROWH 256            // halves per table row (200 used + pad) = 512 B
#define ACOEF 4.0f

// Compiler-only ordering fence (same-wave LDS write->read, HW FIFO).
#define COMPILER_LDS_FENCE() asm volatile("" ::: "memory")

__device__ __forceinline__ float fast_tanh(float a) {
#if __has_builtin(__builtin_amdgcn_exp2f) && __has_builtin(__builtin_amdgcn_rcpf)
    float t = __builtin_amdgcn_exp2f(a * 2.885390081777927f);  // exp(2a)
    return 1.0f - 2.0f * __builtin_amdgcn_rcpf(t + 1.0f);
#else
    float t = exp2f(a * 2.885390081777927f);
    return 1.0f - 2.0f / (t + 1.0f);
#endif
}

// ---------------- fused table build: one dispatch ----
// Block = 256 threads = 2 groups of 128; group g owns tk = blockIdx.x*2+g.
// Stage x[25] -> x2[50] in LDS (block barriers), then thread c computes
// T[t][k][c] (c<100) or pad zero, storing the knot-pair-interleaved f16
// layout: row k halves: 4l+0 = G[k][2l], 4l+1 = G[k][2l+1],
//                       4l+2 = G[k+1][2l], 4l+3 = G[k+1][2l+1].
// Writes are address-disjoint across the grid -> race-free.
__global__ __launch_bounds__(256) void build_table(
    const float* __restrict__ w0, const float* __restrict__ b0,
    const float* __restrict__ w1, const float* __restrict__ b1,
    const float* __restrict__ w2, const float* __restrict__ b2,
    u16* __restrict__ TP)
{
    __shared__ float xs[2][25];
    __shared__ float x2s[2][50];
    const int g = threadIdx.x >> 7, lt = threadIdx.x & 127;
    const int tk = blockIdx.x * 2 + g;              // 0 .. 2*KNOTS-1
    const int t = tk >> 10, k = tk & (KNOTS - 1);
    const float u = (float)k * (1.0f / (float)KNOTS);
    const float s = ACOEF * u / (1.0f - u);

    if (lt < 25)
        xs[g][lt] = fast_tanh(s * w0[t * 25 + lt] + b0[t * 25 + lt]);
    __syncthreads();
    if (lt < 50) {
        float acc = b1[t * 50 + lt];
#pragma unroll
        for (int c = 0; c < 25; ++c) acc += xs[g][c] * w1[t * 1250 + c * 50 + lt];
        x2s[g][lt] = fast_tanh(acc) + xs[g][(lt < 25) ? lt : (lt - 25)];
    }
    __syncthreads();

    const int c = lt;
    const size_t row = (size_t)tk * ROWH;
    const int l4 = 4 * (c >> 1) + (c & 1);
    u16 hb = 0;
    if (c < 100) {
        float acc = b2[t * 100 + c];
#pragma unroll 2
        for (int cc = 0; cc < 50; ++cc) acc += x2s[g][cc] * w2[t * 5000 + cc * 100 + c];
        const float v = fast_tanh(acc) + x2s[g][(c < 50) ? c : (c - 50)];
        const __half h = __float2half(v);
        hb = *reinterpret_cast<const u16*>(&h);
    }
    TP[row + l4] = hb;                        // "k" member of row k (or pad 0)
    if (k > 0) TP[row - ROWH + l4 + 2] = hb;  // "k+1" member of row k-1
}

// ---------------- main: 2 ATOMS PER WAVE for ILP ----------
// Wave owns atoms 2w, 2w+1 (4 waves/block -> 8 atoms/block, grid 1024).
// Phase S runs per atom (independent chains); interp walks both atoms'
// neighbor streams together -> 8 independent table loads in flight per
// 2-neighbor step (latency-bound fix; same total L2 bytes).
__global__ __launch_bounds__(256) void descr_interp(
    const float* __restrict__ coord, const int* __restrict__ atype,
    const int* __restrict__ nlist, const float* __restrict__ mean,
    const float* __restrict__ stddev, const u16* __restrict__ TP,
    float* __restrict__ out_res, float* __restrict__ out_sw)
{
    __shared__ int2 sIF[4][2][NNEI_ + 2];
    const int wave = threadIdx.x >> 6, lane = threadIdx.x & 63;
    const int bbase = (blockIdx.x * 4 + wave) * 2;   // atoms bbase, bbase+1

    // ---- phase S for both atoms: s, sw, (row byte offset, frac) -> LDS ----
#pragma unroll
    for (int a = 0; a < 2; ++a) {
        const int b = bbase + a;
        const int f = b >> 12, il = b & 4095;
        const int aty = atype[f * NALL + il];
        const float cx = coord[(f * NALL + il) * 3 + 0];
        const float cy = coord[(f * NALL + il) * 3 + 1];
        const float cz = coord[(f * NALL + il) * 3 + 2];
#pragma unroll
        for (int p = 0; p < 3; ++p) {
            const int n = p * 64 + lane;
            if (n < NNEI_) {
                const int jn = nlist[b * NNEI_ + n];
                float sw = 0.0f, env = 0.0f;
                if (jn >= 0) {
                    float dx = coord[(f * NALL + jn) * 3 + 0] - cx;
                    float dy = coord[(f * NALL + jn) * 3 + 1] - cy;
                    float dz = coord[(f * NALL + jn) * 3 + 2] - cz;
                    float len = sqrtf(dx * dx + dy * dy + dz * dz);
                    float uu = (len - 0.5f) * (1.0f / 5.5f);
                    float vv = uu * uu * uu * (uu * (-6.0f * uu + 15.0f) - 10.0f) + 1.0f;
                    sw = (len <= 0.5f) ? 1.0f : ((len >= 6.0f) ? 0.0f : vv);
                    env = sw / len;          // len==0 -> +inf (self-neighbor)
                }
                out_sw[b * NNEI_ + n] = sw;
                float s = (env - mean[aty * NNEI_ + n]) / stddev[aty * NNEI_ + n];
                s = fminf(fmaxf(s, 0.0f), 1e7f);   // inf clamp: table saturated
                const float u = s / (s + ACOEF);
                const float pp = u * (float)KNOTS;
                int i = (int)pp;
                i = (i > KNOTS - 2) ? (KNOTS - 2) : i;
                const float fr = pp - (float)i;
                const int off = (((n >= 46) ? KNOTS : 0) + i) * (ROWH * 2); // bytes
                sIF[wave][a][n] = make_int2(off, __float_as_int(fr));
            }
        }
    }
    COMPILER_LDS_FENCE();

    // ---- interp: lane owns cols (2l,2l+1); 2 atoms x 2 neighbors per step ----
    float2 aA0 = {0.f, 0.f}, aA1 = {0.f, 0.f};
    float2 aB0 = {0.f, 0.f}, aB1 = {0.f, 0.f};
    const char* const Tb = (const char*)TP;
    const int loff = lane * 8;

    auto lerp_acc = [&](short4v v, float fr, float2& acc) {
        union { short4v s4; __half2 h2[2]; } cv; cv.s4 = v;
        const __half2 d = __hsub2(cv.h2[1], cv.h2[0]);
        const __half2 r = __hfma2(__float2half2_rn(fr), d, cv.h2[0]);
        acc.x += __low2float(r);
        acc.y += __high2float(r);
    };

#pragma unroll 1
    for (int n = 0; n < NNEI_; n += 2) {   // 138 is even
        const int2 pA0 = sIF[wave][0][n];
        const int2 pA1 = sIF[wave][0][n + 1];
        const int2 pB0 = sIF[wave][1][n];
        const int2 pB1 = sIF[wave][1][n + 1];
        const unsigned sA0 = (unsigned)__builtin_amdgcn_readfirstlane(pA0.x);
        const unsigned sA1 = (unsigned)__builtin_amdgcn_readfirstlane(pA1.x);
        const unsigned sB0 = (unsigned)__builtin_amdgcn_readfirstlane(pB0.x);
        const unsigned sB1 = (unsigned)__builtin_amdgcn_readfirstlane(pB1.x);
        const short4v vA0 = *(const short4v*)(Tb + sA0 + loff);
        const short4v vA1 = *(const short4v*)(Tb + sA1 + loff);
        const short4v vB0 = *(const short4v*)(Tb + sB0 + loff);
        const short4v vB1 = *(const short4v*)(Tb + sB1 + loff);
        lerp_acc(vA0, __int_as_float(pA0.y), aA0);
        lerp_acc(vA1, __int_as_float(pA1.y), aA1);
        lerp_acc(vB0, __int_as_float(pB0.y), aB0);
        lerp_acc(vB1, __int_as_float(pB1.y), aB1);
    }

    if (lane < 50) {
        float2 oA, oB;
        oA.x = (aA0.x + aA1.x) * (0.2f / 138.0f);
        oA.y = (aA0.y + aA1.y) * (0.2f / 138.0f);
        oB.x = (aB0.x + aB1.x) * (0.2f / 138.0f);
        oB.y = (aB0.y + aB1.y) * (0.2f / 138.0f);
        *reinterpret_cast<float2*>(out_res + (size_t)bbase * 100 + 2 * lane) = oA;
        *reinterpret_cast<float2*>(out_res + (size_t)(bbase + 1) * 100 + 2 * lane) = oB;
    }
}

extern "C" void kernel_launch(void* const* d_in, const int* in_sizes, int n_in,
                              void* d_out, int out_size, void* d_ws, size_t ws_size,
                              hipStream_t stream) {
    const float* coord  = (const float*)d_in[0];
    const int*   atype  = (const int*)d_in[1];
    const int*   nlist  = (const int*)d_in[2];
    const float* mean   = (const float*)d_in[3];
    const float* stddev = (const float*)d_in[4];
    const float* w0 = (const float*)d_in[5];
    const float* b0 = (const float*)d_in[6];
    const float* w1 = (const float*)d_in[7];
    const float* b1 = (const float*)d_in[8];
    const float* w2 = (const float*)d_in[9];
    const float* b2 = (const float*)d_in[10];

    u16* TP = (u16*)d_ws;                           // [2][KNOTS][ROWH] f16 = 1 MB
    float* out_res = (float*)d_out;                 // [2][4096][100]
    float* out_sw  = out_res + NF * NLOC * 100;     // [2][4096][138]

    hipLaunchKernelGGL(build_table, dim3(KNOTS), dim3(256), 0, stream,
                       w0, b0, w1, b1, w2, b2, TP);
    hipLaunchKernelGGL(descr_interp, dim3((NF * NLOC) / 8), dim3(256), 0, stream,
                       coord, atype, nlist, mean, stddev, TP, out_res, out_sw);
}

// Round 23
// 48.499 us; speedup vs baseline: 1.0093x; 1.0093x over previous
//
#include <hip/hip_runtime.h>
#include <hip/hip_bf16.h>
#include <hip/hip_fp16.h>

typedef unsigned short u16;
typedef __attribute__((ext_vector_type(4))) short short4v;

#define NF 2
#define NLOC 4096
#define NALL 8192
#define NNEI_ 138
#define KNOTS 1024          // knots per type; u_k = k/KNOTS, s = A*u/(1-u)
#define ROWH 256            // halves per table row (200 used + pad) = 512 B
#define ACOEF 4.0f

// Compiler-only ordering fence (same-wave LDS write->read, HW FIFO).
#define COMPILER_LDS_FENCE() asm volatile("" ::: "memory")

__device__ __forceinline__ float fast_tanh(float a) {
#if __has_builtin(__builtin_amdgcn_exp2f) && __has_builtin(__builtin_amdgcn_rcpf)
    float t = __builtin_amdgcn_exp2f(a * 2.885390081777927f);  // exp(2a)
    return 1.0f - 2.0f * __builtin_amdgcn_rcpf(t + 1.0f);
#else
    float t = exp2f(a * 2.885390081777927f);
    return 1.0f - 2.0f / (t + 1.0f);
#endif
}

// ---------------- fused table build: one dispatch ----
// Block = 256 threads = 2 groups of 128; group g owns tk = blockIdx.x*2+g.
// Stage x[25] -> x2[50] in LDS (block barriers), then thread c computes
// T[t][k][c] (c<100) or pad zero, storing the knot-pair-interleaved f16
// layout: row k halves: 4l+0 = G[k][2l], 4l+1 = G[k][2l+1],
//                       4l+2 = G[k+1][2l], 4l+3 = G[k+1][2l+1].
// Writes are address-disjoint across the grid -> race-free.
__global__ __launch_bounds__(256) void build_table(
    const float* __restrict__ w0, const float* __restrict__ b0,
    const float* __restrict__ w1, const float* __restrict__ b1,
    const float* __restrict__ w2, const float* __restrict__ b2,
    u16* __restrict__ TP)
{
    __shared__ float xs[2][25];
    __shared__ float x2s[2][50];
    const int g = threadIdx.x >> 7, lt = threadIdx.x & 127;
    const int tk = blockIdx.x * 2 + g;              // 0 .. 2*KNOTS-1
    const int t = tk >> 10, k = tk & (KNOTS - 1);
    const float u = (float)k * (1.0f / (float)KNOTS);
    const float s = ACOEF * u / (1.0f - u);

    if (lt < 25)
        xs[g][lt] = fast_tanh(s * w0[t * 25 + lt] + b0[t * 25 + lt]);
    __syncthreads();
    if (lt < 50) {
        float acc = b1[t * 50 + lt];
#pragma unroll
        for (int c = 0; c < 25; ++c) acc += xs[g][c] * w1[t * 1250 + c * 50 + lt];
        x2s[g][lt] = fast_tanh(acc) + xs[g][(lt < 25) ? lt : (lt - 25)];
    }
    __syncthreads();

    const int c = lt;
    const size_t row = (size_t)tk * ROWH;
    const int l4 = 4 * (c >> 1) + (c & 1);
    u16 hb = 0;
    if (c < 100) {
        float acc = b2[t * 100 + c];
#pragma unroll 2
        for (int cc = 0; cc < 50; ++cc) acc += x2s[g][cc] * w2[t * 5000 + cc * 100 + c];
        const float v = fast_tanh(acc) + x2s[g][(c < 50) ? c : (c - 50)];
        const __half h = __float2half(v);
        hb = *reinterpret_cast<const u16*>(&h);
    }
    TP[row + l4] = hb;                        // "k" member of row k (or pad 0)
    if (k > 0) TP[row - ROWH + l4 + 2] = hb;  // "k+1" member of row k-1
}

// ---------------- main: 1 atom/wave, interp unrolled 8 ----------
// Phase S (3 passes, lanes parallel): exact s math + index precompute -> LDS.
// Interp loop: 8 independent table loads in flight per wave (latency hiding
// at CONSTANT wave count — R22 showed ILP-for-TLP trades are neutral);
// sIF fetched as int4 (1 ds_read_b128 per 2 neighbors).
__global__ __launch_bounds__(256) void descr_interp(
    const float* __restrict__ coord, const int* __restrict__ atype,
    const int* __restrict__ nlist, const float* __restrict__ mean,
    const float* __restrict__ stddev, const u16* __restrict__ TP,
    float* __restrict__ out_res, float* __restrict__ out_sw)
{
    __shared__ __align__(16) int2 sIF[4][NNEI_ + 2];   // 140 int2 = 1120 B/wave (16B-mult)
    const int wave = threadIdx.x >> 6, lane = threadIdx.x & 63;
    const int b = blockIdx.x * 4 + wave;
    const int f = b >> 12, il = b & 4095;

    const int aty = atype[f * NALL + il];
    const float cx = coord[(f * NALL + il) * 3 + 0];
    const float cy = coord[(f * NALL + il) * 3 + 1];
    const float cz = coord[(f * NALL + il) * 3 + 2];

    // ---- phase S: s, sw, and (row byte offset, frac) for all 138 slots ----
#pragma unroll
    for (int p = 0; p < 3; ++p) {
        const int n = p * 64 + lane;
        if (n < NNEI_) {
            const int jn = nlist[b * NNEI_ + n];
            float sw = 0.0f, env = 0.0f;
            if (jn >= 0) {
                float dx = coord[(f * NALL + jn) * 3 + 0] - cx;
                float dy = coord[(f * NALL + jn) * 3 + 1] - cy;
                float dz = coord[(f * NALL + jn) * 3 + 2] - cz;
                float len = sqrtf(dx * dx + dy * dy + dz * dz);
                float uu = (len - 0.5f) * (1.0f / 5.5f);
                float vv = uu * uu * uu * (uu * (-6.0f * uu + 15.0f) - 10.0f) + 1.0f;
                sw = (len <= 0.5f) ? 1.0f : ((len >= 6.0f) ? 0.0f : vv);
                env = sw / len;          // len==0 -> +inf (self-neighbor)
            }
            out_sw[b * NNEI_ + n] = sw;
            float s = (env - mean[aty * NNEI_ + n]) / stddev[aty * NNEI_ + n];
            s = fminf(fmaxf(s, 0.0f), 1e7f);   // inf clamp: table saturated there
            const float u = s / (s + ACOEF);
            const float pp = u * (float)KNOTS;
            int i = (int)pp;
            i = (i > KNOTS - 2) ? (KNOTS - 2) : i;
            const float fr = pp - (float)i;
            const int off = (((n >= 46) ? KNOTS : 0) + i) * (ROWH * 2); // bytes
            sIF[wave][n] = make_int2(off, __float_as_int(fr));
        }
    }
    COMPILER_LDS_FENCE();

    // ---- interp: lane owns cols (2l, 2l+1); 8 neighbors per iteration ----
    float2 ac[4];
    ac[0] = {0.f, 0.f}; ac[1] = {0.f, 0.f}; ac[2] = {0.f, 0.f}; ac[3] = {0.f, 0.f};
    const char* const Tb = (const char*)TP;
    const int loff = lane * 8;

    auto lerp_acc = [&](short4v v, float fr, float2& acc) {
        union { short4v s4; __half2 h2[2]; } cv; cv.s4 = v;
        const __half2 d = __hsub2(cv.h2[1], cv.h2[0]);
        const __half2 r = __hfma2(__float2half2_rn(fr), d, cv.h2[0]);
        acc.x += __low2float(r);
        acc.y += __high2float(r);
    };

#pragma unroll 1
    for (int n = 0; n < 136; n += 8) {   // 138 = 8*17 + 2
        const int4 q0 = *(const int4*)&sIF[wave][n + 0];   // nbrs n, n+1
        const int4 q1 = *(const int4*)&sIF[wave][n + 2];
        const int4 q2 = *(const int4*)&sIF[wave][n + 4];
        const int4 q3 = *(const int4*)&sIF[wave][n + 6];
        const unsigned s0 = (unsigned)__builtin_amdgcn_readfirstlane(q0.x);
        const unsigned s1 = (unsigned)__builtin_amdgcn_readfirstlane(q0.z);
        const unsigned s2 = (unsigned)__builtin_amdgcn_readfirstlane(q1.x);
        const unsigned s3 = (unsigned)__builtin_amdgcn_readfirstlane(q1.z);
        const unsigned s4 = (unsigned)__builtin_amdgcn_readfirstlane(q2.x);
        const unsigned s5 = (unsigned)__builtin_amdgcn_readfirstlane(q2.z);
        const unsigned s6 = (unsigned)__builtin_amdgcn_readfirstlane(q3.x);
        const unsigned s7 = (unsigned)__builtin_amdgcn_readfirstlane(q3.z);
        const short4v v0 = *(const short4v*)(Tb + s0 + loff);
        const short4v v1 = *(const short4v*)(Tb + s1 + loff);
        const short4v v2 = *(const short4v*)(Tb + s2 + loff);
        const short4v v3 = *(const short4v*)(Tb + s3 + loff);
        const short4v v4 = *(const short4v*)(Tb + s4 + loff);
        const short4v v5 = *(const short4v*)(Tb + s5 + loff);
        const short4v v6 = *(const short4v*)(Tb + s6 + loff);
        const short4v v7 = *(const short4v*)(Tb + s7 + loff);
        lerp_acc(v0, __int_as_float(q0.y), ac[0]);
        lerp_acc(v1, __int_as_float(q0.w), ac[1]);
        lerp_acc(v2, __int_as_float(q1.y), ac[2]);
        lerp_acc(v3, __int_as_float(q1.w), ac[3]);
        lerp_acc(v4, __int_as_float(q2.y), ac[0]);
        lerp_acc(v5, __int_as_float(q2.w), ac[1]);
        lerp_acc(v6, __int_as_float(q3.y), ac[2]);
        lerp_acc(v7, __int_as_float(q3.w), ac[3]);
    }
    {   // tail: n = 136, 137
        const int4 q0 = *(const int4*)&sIF[wave][136];
        const unsigned s0 = (unsigned)__builtin_amdgcn_readfirstlane(q0.x);
        const unsigned s1 = (unsigned)__builtin_amdgcn_readfirstlane(q0.z);
        const short4v v0 = *(const short4v*)(Tb + s0 + loff);
        const short4v v1 = *(const short4v*)(Tb + s1 + loff);
        lerp_acc(v0, __int_as_float(q0.y), ac[0]);
        lerp_acc(v1, __int_as_float(q0.w), ac[1]);
    }

    if (lane < 50) {
        float2 o;
        o.x = (ac[0].x + ac[1].x + ac[2].x + ac[3].x) * (0.2f / 138.0f);
        o.y = (ac[0].y + ac[1].y + ac[2].y + ac[3].y) * (0.2f / 138.0f);
        *reinterpret_cast<float2*>(out_res + (size_t)b * 100 + 2 * lane) = o;
    }
}

extern "C" void kernel_launch(void* const* d_in, const int* in_sizes, int n_in,
                              void* d_out, int out_size, void* d_ws, size_t ws_size,
                              hipStream_t stream) {
    const float* coord  = (const float*)d_in[0];
    const int*   atype  = (const int*)d_in[1];
    const int*   nlist  = (const int*)d_in[2];
    const float* mean   = (const float*)d_in[3];
    const float* stddev = (const float*)d_in[4];
    const float* w0 = (const float*)d_in[5];
    const float* b0 = (const float*)d_in[6];
    const float* w1 = (const float*)d_in[7];
    const float* b1 = (const float*)d_in[8];
    const float* w2 = (const float*)d_in[9];
    const float* b2 = (const float*)d_in[10];

    u16* TP = (u16*)d_ws;                           // [2][KNOTS][ROWH] f16 = 1 MB
    float* out_res = (float*)d_out;                 // [2][4096][100]
    float* out_sw  = out_res + NF * NLOC * 100;     // [2][4096][138]

    hipLaunchKernelGGL(build_table, dim3(KNOTS), dim3(256), 0, stream,
                       w0, b0, w1, b1, w2, b2, TP);
    hipLaunchKernelGGL(descr_interp, dim3((NF * NLOC) / 4), dim3(256), 0, stream,
                       coord, atype, nlist, mean, stddev, TP, out_res, out_sw);
}